// Round 8
// baseline (407.701 us; speedup 1.0000x reference)
//
#include <hip/hip_runtime.h>

#define MDIM 8192
#define NDIM 4096
#define KDIM 4096

typedef int v4i __attribute__((ext_vector_type(4)));
typedef int v16i __attribute__((ext_vector_type(16)));

__device__ __forceinline__ unsigned pack4(int x, int y, int z, int w) {
    return (unsigned)(x & 0xff) | ((unsigned)(y & 0xff) << 8) |
           ((unsigned)(z & 0xff) << 16) | ((unsigned)w << 24);
}

// ---- pass 1: int32 -> packed int8, pre-tiled ---- (unchanged)
// A and B tiles: 256 rows x 128 k, granule-major [kb 0..7][row 0..255],
// granule = 16 B of k for one row == exact MFMA fragment order.
__global__ __launch_bounds__(256) void pack_tiled(const int* __restrict__ x,
                                                  const int* __restrict__ w,
                                                  uint4* __restrict__ xp,
                                                  uint4* __restrict__ wp) {
    __shared__ unsigned lds32[256 * 33];
    const int wg  = blockIdx.x;
    const int tid = threadIdx.x;
    const int kq   = tid & 31;
    const int rsub = tid >> 5;

    const int* src;
    uint4* dst;
    if (wg < 1024) {
        const int mtile = wg >> 5, kiter = wg & 31;
        src = x + (size_t)(mtile * 256) * KDIM + kiter * 128;
        dst = xp + (size_t)(mtile * 32 + kiter) * 2048;
    } else {
        const int ntile = (wg - 1024) >> 5, kiter = wg & 31;
        src = w + (size_t)(ntile * 256) * KDIM + kiter * 128;
        dst = wp + (size_t)(ntile * 32 + kiter) * 2048;
    }
#pragma unroll
    for (int it = 0; it < 32; ++it) {
        const int row = it * 8 + rsub;
        int4 v = *(const int4*)(src + (size_t)row * KDIM + kq * 4);
        lds32[row * 33 + kq] = pack4(v.x, v.y, v.z, v.w);
    }
    __syncthreads();
#pragma unroll
    for (int it = 0; it < 8; ++it) {
        const int g = it * 256 + tid;
        const int kb = g >> 8, row = g & 255;
        const unsigned* p = &lds32[row * 33 + kb * 4];
        uint4 o;
        o.x = p[0]; o.y = p[1]; o.z = p[2]; o.w = p[3];
        dst[g] = o;
    }
}

// ---- pass 2: int8 GEMM, out = x @ W^T ----
// R8: OCCUPANCY + BLOCK-TLP. R0-R7 invariant: MfmaUtil ~47% at 2 waves/
// SIMD, 1 block/CU -- every barrier idles the whole CU; no independent
// stream exists to fill staging/wait phases, and the i8 MFMA pipe has
// only 2 streams to issue from. Re-geometry:
//   128x128 block, 256 threads (2x2 waves), wave tile 64x64 (acc[2][2]
//   = 64 AGPR), BK=64. LDS 32 KB/block = A+B double-buffered 2x16 KB.
//   -> ~105 VGPR/wave (launch_bounds(256,4) caps 128), 4 blocks/CU,
//   16 waves/CU, 4 waves/SIMD FROM 4 INDEPENDENT BLOCKS. While one
//   block drains its barrier/DMA, three others issue MFMA.
// Pack layout unchanged: GEMM addresses 128-row/64-k subtiles of the
// 256-row/128-k pack tiles. For row r, 16B-granule kb (=k/16):
//   off = ((r>>8)*32 + (kb>>3))*2048 + (kb&7)*256 + (r&255)   [granules]
// For bm0=by*128, tile t (k0=64t): kb = 4t+kl, kl=0..3 ->
//   tilebase advances UNIFORMLY by 16 KB per t:
//   apan(t) = Ap + (by>>1)*1 MB + ((tid>>7)*256 + (by&1)*128 + (tid&127))*16
//             + t*16384,  staged chunk c at +c*8192.
// LDS [kl 0..3][row 0..127] granule-major == fragment order; ds_read_b128
// conflict-free; gload_lds dest linear tid*16.
__global__ __launch_bounds__(256, 4) void gemm_i8_tlp(const char* __restrict__ Ap,
                                                      const char* __restrict__ Bp,
                                                      const _Float16* __restrict__ bias,
                                                      _Float16* __restrict__ out) {
    __shared__ __align__(16) char lds[32768];

    const int tid  = threadIdx.x;
    const int lane = tid & 63;
    const int wave = tid >> 6;
    const int wr   = wave >> 1;   // 0..1 (M half of 128)
    const int wc   = wave & 1;    // 0..1 (N half of 128)
    const int l31  = lane & 31;
    const int kg   = lane >> 5;

    // bijective XCD-chunked swizzle: 2048 blocks (32 bx x 64 by), 8 XCDs,
    // each XCD a 16bx x 16by region (256 blocks).
    const int lid = blockIdx.y * 32 + blockIdx.x;
    const int xcd = lid & 7, ii = lid >> 3;          // ii 0..255
    const int bx  = (xcd & 1) * 16 + (ii & 15);      // 0..31
    const int by  = (xcd >> 1) * 16 + (ii >> 4);     // 0..63
    const int bm0 = by * 128;
    const int bn0 = bx * 128;

    const char* apan = Ap + (size_t)(by >> 1) * 1048576
                     + (((tid >> 7) * 256) + (by & 1) * 128 + (tid & 127)) * 16;
    const char* bpan = Bp + (size_t)(bx >> 1) * 1048576
                     + (((tid >> 7) * 256) + (bx & 1) * 128 + (tid & 127)) * 16;

    int aoffr[2], boffr[2];
#pragma unroll
    for (int mt = 0; mt < 2; ++mt)
        aoffr[mt] = (wr * 64 + mt * 32 + l31) * 16;
#pragma unroll
    for (int nt = 0; nt < 2; ++nt)
        boffr[nt] = 8192 + (wc * 64 + nt * 32 + l31) * 16;

    v16i acc[2][2];
#pragma unroll
    for (int mt = 0; mt < 2; ++mt)
#pragma unroll
        for (int nt = 0; nt < 2; ++nt)
#pragma unroll
            for (int i = 0; i < 16; ++i) acc[mt][nt][i] = 0;

    v4i afP[2], afQ[2], bf[2][2];

    // stage tile into LDS buffer nb: A 8 KB (2 chunks) + B 8 KB (2 chunks)
    auto stage = [&](int nb) {
#pragma unroll
        for (int c = 0; c < 2; ++c)
            __builtin_amdgcn_global_load_lds(
                (__attribute__((address_space(1))) const void*)(apan + c * 8192),
                (__attribute__((address_space(3))) void*)(lds + nb + c * 4096 + tid * 16),
                16, 0, 0);
#pragma unroll
        for (int c = 0; c < 2; ++c)
            __builtin_amdgcn_global_load_lds(
                (__attribute__((address_space(1))) const void*)(bpan + c * 8192),
                (__attribute__((address_space(3))) void*)(lds + nb + 8192 + c * 4096 + tid * 16),
                16, 0, 0);
        apan += 16384;
        bpan += 16384;
    };
    auto readA = [&](v4i (&d)[2], int base, int ks) {  // 2 ds_read_b128
#pragma unroll
        for (int mt = 0; mt < 2; ++mt)
            d[mt] = *(const v4i*)(lds + base + (2 * ks + kg) * 2048 + aoffr[mt]);
    };
    auto readB = [&](int base) {  // 4 ds_read_b128
#pragma unroll
        for (int nt = 0; nt < 2; ++nt)
#pragma unroll
            for (int ks = 0; ks < 2; ++ks)
                bf[nt][ks] = *(const v4i*)(lds + base + (2 * ks + kg) * 2048 + boffr[nt]);
    };
    auto cl = [&](const v4i (&a)[2], int k) {  // 4 MFMA
        __builtin_amdgcn_s_setprio(1);
#pragma unroll
        for (int mt = 0; mt < 2; ++mt)
#pragma unroll
            for (int nt = 0; nt < 2; ++nt)
                acc[mt][nt] = __builtin_amdgcn_mfma_i32_32x32x32_i8(
                    a[mt], bf[nt][k], acc[mt][nt], 0, 0, 0);
        __builtin_amdgcn_s_setprio(0);
    };

#define SB0 __builtin_amdgcn_sched_barrier(0)
#define TOPBAR do { asm volatile("s_waitcnt vmcnt(0)" ::: "memory"); \
                    __builtin_amdgcn_s_barrier(); } while (0)

    // prologue: stage tile 0 -> buf0, full drain
    stage(0);
    TOPBAR; SB0;

#pragma unroll 1
    for (int t = 0; t < 64; ++t) {
        const int cur = (t & 1) ? 16384 : 0;
        if (t < 63) stage(cur ^ 16384);   // DMA tile t+1 (covered by body)
        readB(cur);
        readA(afP, cur, 0);
        SB0;
        readA(afQ, cur, 1);
        SB0;
        cl(afP, 0);                       // ks0 (afQ reads service under it)
        SB0;
        cl(afQ, 1);                       // ks1
        if (t < 63) { TOPBAR; }           // drain stage(t+1); block-level TLP
                                          // hides this under other blocks
    }

#undef SB0
#undef TOPBAR

    // epilogue: int32 -> fp16 (exact; overflow -> inf matches ref), + bias.
    // C/D layout: col=lane&31, row=(reg&3)+8*(reg>>2)+4*(lane>>5)
    const _Float16 bv0 = bias[bn0 + wc * 64 + l31];
    const _Float16 bv1 = bias[bn0 + wc * 64 + 32 + l31];
#pragma unroll
    for (int mt = 0; mt < 2; ++mt) {
#pragma unroll
        for (int nt = 0; nt < 2; ++nt) {
            const int gcol = bn0 + wc * 64 + nt * 32 + l31;
            const _Float16 bb = nt ? bv1 : bv0;
#pragma unroll
            for (int r = 0; r < 16; ++r) {
                const int rit  = (r & 3) + 8 * (r >> 2) + 4 * kg;
                const int grow = bm0 + wr * 64 + mt * 32 + rit;
                _Float16 h = (_Float16)(float)acc[mt][nt][r] + bb;
                out[(size_t)grow * NDIM + gcol] = h;
            }
        }
    }
}

// ---- fallback (no workspace): non-pipelined, packs in regs ---- (unchanged)
__global__ __launch_bounds__(256, 2) void gemm_i8_fb(const int* __restrict__ A32,
                                                     const int* __restrict__ B32,
                                                     const _Float16* __restrict__ bias,
                                                     _Float16* __restrict__ out) {
    __shared__ char lds[32768];
    const int tid  = threadIdx.x;
    const int lane = tid & 63;
    const int wave = tid >> 6;
    const int bm0 = blockIdx.y * 256;
    const int bn0 = blockIdx.x * 128;
    const int wr  = wave >> 1;
    const int wc  = wave & 1;
    const int l31 = lane & 31;
    const int kg  = lane >> 5;

    int abase[4];
#pragma unroll
    for (int mt = 0; mt < 4; ++mt)
        abase[mt] = kg * 4096 + (wr * 128 + mt * 32 + l31) * 16;

    v16i acc[4][2];
#pragma unroll
    for (int mt = 0; mt < 4; ++mt)
#pragma unroll
        for (int nt = 0; nt < 2; ++nt)
#pragma unroll
            for (int i = 0; i < 16; ++i) acc[mt][nt][i] = 0;

    int aoffs[8];
#pragma unroll
    for (int r = 0; r < 8; ++r) {
        const int c = r * 4 + wave;
        aoffs[r] = (bm0 + (c & 3) * 64 + lane) * KDIM + (c >> 2) * 16;
    }
    for (int k0 = 0; k0 < KDIM; k0 += 128) {
        v4i bfx[2][4];
#pragma unroll
        for (int r = 0; r < 8; ++r) {
            const int c = r * 4 + wave;
            const int4* s = (const int4*)(A32 + (size_t)aoffs[r]);
            int4 v0 = s[0], v1 = s[1], v2 = s[2], v3 = s[3];
            uint4 pk;
            pk.x = pack4(v0.x, v0.y, v0.z, v0.w);
            pk.y = pack4(v1.x, v1.y, v1.z, v1.w);
            pk.z = pack4(v2.x, v2.y, v2.z, v2.w);
            pk.w = pack4(v3.x, v3.y, v3.z, v3.w);
            *(uint4*)(lds + c * 1024 + lane * 16) = pk;
            aoffs[r] += 128;
        }
#pragma unroll
        for (int nt = 0; nt < 2; ++nt)
#pragma unroll
            for (int ks = 0; ks < 4; ++ks) {
                const int* s = B32 + (size_t)(bn0 + wc * 64 + nt * 32 + l31) * KDIM
                               + k0 + (2 * ks + kg) * 16;
                int4 v0 = ((const int4*)s)[0], v1 = ((const int4*)s)[1];
                int4 v2 = ((const int4*)s)[2], v3 = ((const int4*)s)[3];
                bfx[nt][ks][0] = (int)pack4(v0.x, v0.y, v0.z, v0.w);
                bfx[nt][ks][1] = (int)pack4(v1.x, v1.y, v1.z, v1.w);
                bfx[nt][ks][2] = (int)pack4(v2.x, v2.y, v2.z, v2.w);
                bfx[nt][ks][3] = (int)pack4(v3.x, v3.y, v3.z, v3.w);
            }
        __syncthreads();
#pragma unroll
        for (int ks = 0; ks < 4; ++ks) {
            v4i afr[4];
#pragma unroll
            for (int mt = 0; mt < 4; ++mt)
                afr[mt] = *(const v4i*)(lds + abase[mt] + ks * 8192);
#pragma unroll
            for (int mt = 0; mt < 4; ++mt)
#pragma unroll
                for (int nt = 0; nt < 2; ++nt)
                    acc[mt][nt] = __builtin_amdgcn_mfma_i32_32x32x32_i8(
                        afr[mt], bfx[nt][ks], acc[mt][nt], 0, 0, 0);
        }
        __syncthreads();
    }

    const _Float16 bv0 = bias[bn0 + wc * 64 + l31];
    const _Float16 bv1 = bias[bn0 + wc * 64 + 32 + l31];
#pragma unroll
    for (int mt = 0; mt < 4; ++mt) {
#pragma unroll
        for (int nt = 0; nt < 2; ++nt) {
            const int gcol = bn0 + wc * 64 + nt * 32 + l31;
            const _Float16 bb = nt ? bv1 : bv0;
#pragma unroll
            for (int r = 0; r < 16; ++r) {
                const int rit  = (r & 3) + 8 * (r >> 2) + 4 * kg;
                const int grow = bm0 + wr * 128 + mt * 32 + rit;
                _Float16 h = (_Float16)(float)acc[mt][nt][r] + bb;
                out[(size_t)grow * NDIM + gcol] = h;
            }
        }
    }
}

extern "C" void kernel_launch(void* const* d_in, const int* in_sizes, int n_in,
                              void* d_out, int out_size, void* d_ws, size_t ws_size,
                              hipStream_t stream) {
    const int* x = (const int*)d_in[0];
    const int* w = (const int*)d_in[1];
    const _Float16* bias = (const _Float16*)d_in[2];
    _Float16* out = (_Float16*)d_out;

    const size_t xbytes = (size_t)MDIM * KDIM;  // packed int8 bytes
    const size_t wbytes = (size_t)NDIM * KDIM;

    if (ws_size >= xbytes + wbytes) {
        char* xp = (char*)d_ws;
        char* wp = xp + xbytes;
        pack_tiled<<<1536, 256, 0, stream>>>(x, w, (uint4*)xp, (uint4*)wp);
        gemm_i8_tlp<<<dim3(32, 64), 256, 0, stream>>>(
            (const char*)xp, (const char*)wp, bias, out);
    } else {
        gemm_i8_fb<<<dim3(NDIM / 128, MDIM / 256), 256, 0, stream>>>(
            x, w, bias, out);
    }
}